// Round 4
// baseline (504.632 us; speedup 1.0000x reference)
//
#include <hip/hip_runtime.h>
#include <math.h>

#define KC 24
constexpr int D = 16;
constexpr int B = 4;
constexpr int N = 512 * 1024;          // points per image, 2^19
constexpr float DELTA_VAR = 1.0f;
constexpr float DELTA_DIST = 2.0f;

constexpr int REP = 8;                 // LDS bin replicas (replica = lane&7)
constexpr int CS  = 33;                // replica stride (distinct bank offsets)
constexpr int CHUNK = 16384;           // floats per (b,d,chunk) block = 64 KB run
constexpr int NCH = N / CHUNK;         // 32
constexpr int SBLOCKS = B * D * NCH;   // 2048

constexpr int VPTS = 2048;             // k_var points per block (8 KB run per plane)
constexpr int VBLOCKS = (B * N) / VPTS;// 1024

// ws (floats): g_sums [B*KC*D]=1536 | g_cnt [B*KC]=96 | g_varp [64]

// ---------------- Pass 1: plane-major, fully sequential 64 KB streams ----------------
__global__ __launch_bounds__(256) void k_sums(const float* __restrict__ data,
                                              const int* __restrict__ labels,
                                              float* __restrict__ g_sums,
                                              float* __restrict__ g_cnt) {
    __shared__ float s_sum[REP * CS];
    __shared__ float s_cnt[REP * CS];
    const int t   = threadIdx.x;
    const int idx = blockIdx.x;
    const int d   = idx & 15;              // fastest: 16 d-blocks share one label chunk
    const int c   = (idx >> 4) & (NCH - 1);
    const int b   = idx >> 9;

    for (int i = t; i < REP * CS; i += 256) { s_sum[i] = 0.f; s_cnt[i] = 0.f; }
    __syncthreads();

    const float* dp = data  + ((size_t)b * D + d) * N + (size_t)c * CHUNK;
    const int*   lp = labels + (size_t)b * N          + (size_t)c * CHUNK;
    const int rb = (t & 7) * CS;

    if (d == 0) {
        for (int i = t * 4; i < CHUNK; i += 1024) {
            float4 v = *(const float4*)(dp + i);
            int4   l = *(const int4*)(lp + i);
            atomicAdd(&s_sum[rb + l.x], v.x);
            atomicAdd(&s_sum[rb + l.y], v.y);
            atomicAdd(&s_sum[rb + l.z], v.z);
            atomicAdd(&s_sum[rb + l.w], v.w);
            atomicAdd(&s_cnt[rb + l.x], 1.f);
            atomicAdd(&s_cnt[rb + l.y], 1.f);
            atomicAdd(&s_cnt[rb + l.z], 1.f);
            atomicAdd(&s_cnt[rb + l.w], 1.f);
        }
    } else {
        for (int i = t * 4; i < CHUNK; i += 1024) {
            float4 v = *(const float4*)(dp + i);
            int4   l = *(const int4*)(lp + i);
            atomicAdd(&s_sum[rb + l.x], v.x);
            atomicAdd(&s_sum[rb + l.y], v.y);
            atomicAdd(&s_sum[rb + l.z], v.z);
            atomicAdd(&s_sum[rb + l.w], v.w);
        }
    }
    __syncthreads();

    if (t < KC) {
        float s = 0.f;
#pragma unroll
        for (int r = 0; r < REP; ++r) s += s_sum[r * CS + t];
        atomicAdd(&g_sums[(b * KC + t) * D + d], s);
    }
    if (d == 0 && t >= 64 && t < 64 + KC) {
        const int k = t - 64;
        float s = 0.f;
#pragma unroll
        for (int r = 0; r < REP; ++r) s += s_cnt[r * CS + k];
        atomicAdd(&g_cnt[b * KC + k], s);
    }
}

// ---------------- Pass 2: hinged variance, 8 KB runs, 2-deep MLP ----------------
// var_sum = sum_n h_n^2 / cnt[lab_n]  (pure scalar reduction, no LDS atomics)
__global__ __launch_bounds__(256) void k_var(const float* __restrict__ data,
                                             const int* __restrict__ labels,
                                             const float* __restrict__ g_sums,
                                             const float* __restrict__ g_cnt,
                                             float* __restrict__ g_varp) {
    __shared__ float s_c[KC * 17];
    __shared__ float s_ic[KC];
    __shared__ float s_part[4];
    const int t = threadIdx.x;
    const int chunk = blockIdx.x * VPTS;
    const int b     = chunk >> 19;
    const int n0    = chunk & (N - 1);

    for (int i = t; i < KC * D; i += 256) {
        int k = i >> 4, d = i & 15;
        s_c[k * 17 + d] = g_sums[i + b * (KC * D)] / g_cnt[b * KC + k];
    }
    if (t < KC) s_ic[t] = 1.f / g_cnt[b * KC + t];
    __syncthreads();

    const int4 l0 = *(const int4*)(labels + chunk + t * 4);
    const int4 l1 = *(const int4*)(labels + chunk + 1024 + t * 4);
    const int a0x = l0.x * 17, a0y = l0.y * 17, a0z = l0.z * 17, a0w = l0.w * 17;
    const int a1x = l1.x * 17, a1y = l1.y * 17, a1z = l1.z * 17, a1w = l1.w * 17;

    const float* base = data + (size_t)(b * D) * N + n0 + t * 4;
    float4 q0 = {0.f, 0.f, 0.f, 0.f};
    float4 q1 = {0.f, 0.f, 0.f, 0.f};
#pragma unroll
    for (int d = 0; d < D; ++d) {
        float4 v0 = *(const float4*)(base + (size_t)d * N);
        float4 v1 = *(const float4*)(base + (size_t)d * N + 1024);
        float df;
        df = v0.x - s_c[a0x + d]; q0.x += df * df;
        df = v0.y - s_c[a0y + d]; q0.y += df * df;
        df = v0.z - s_c[a0z + d]; q0.z += df * df;
        df = v0.w - s_c[a0w + d]; q0.w += df * df;
        df = v1.x - s_c[a1x + d]; q1.x += df * df;
        df = v1.y - s_c[a1y + d]; q1.y += df * df;
        df = v1.z - s_c[a1z + d]; q1.z += df * df;
        df = v1.w - s_c[a1w + d]; q1.w += df * df;
    }
    float h, hsum;
    h = fmaxf(sqrtf(q0.x) - DELTA_VAR, 0.f); hsum  = h * h * s_ic[l0.x];
    h = fmaxf(sqrtf(q0.y) - DELTA_VAR, 0.f); hsum += h * h * s_ic[l0.y];
    h = fmaxf(sqrtf(q0.z) - DELTA_VAR, 0.f); hsum += h * h * s_ic[l0.z];
    h = fmaxf(sqrtf(q0.w) - DELTA_VAR, 0.f); hsum += h * h * s_ic[l0.w];
    h = fmaxf(sqrtf(q1.x) - DELTA_VAR, 0.f); hsum += h * h * s_ic[l1.x];
    h = fmaxf(sqrtf(q1.y) - DELTA_VAR, 0.f); hsum += h * h * s_ic[l1.y];
    h = fmaxf(sqrtf(q1.z) - DELTA_VAR, 0.f); hsum += h * h * s_ic[l1.z];
    h = fmaxf(sqrtf(q1.w) - DELTA_VAR, 0.f); hsum += h * h * s_ic[l1.w];

    for (int o = 32; o > 0; o >>= 1) hsum += __shfl_down(hsum, o, 64);
    if ((t & 63) == 0) s_part[t >> 6] = hsum;
    __syncthreads();
    if (t == 0)
        atomicAdd(&g_varp[blockIdx.x & 63],
                  s_part[0] + s_part[1] + s_part[2] + s_part[3]);
}

// ---------------- Finalize ----------------
__global__ __launch_bounds__(128) void k_final(const float* __restrict__ g_sums,
                                               const float* __restrict__ g_cnt,
                                               const float* __restrict__ g_varp,
                                               float* __restrict__ out) {
    __shared__ float s_c[B * KC * 17];
    __shared__ float s_red[2];
    const int t = threadIdx.x;

    float acc = 0.f;
    if (t < B * KC) {
        float cnt = g_cnt[t];
        float ns = 0.f;
        for (int d = 0; d < D; ++d) {
            float c = g_sums[t * D + d] / cnt;
            s_c[t * 17 + d] = c;
            ns += c * c;
        }
        acc = sqrtf(ns) / (float)KC;
    }
    if (t < 64) acc += g_varp[t];
    __syncthreads();

    float dacc = 0.f;  // raw sum over [B,K,K] incl. diagonal (= delta_dist^2 each)
    for (int idx = t; idx < B * KC * KC; idx += 128) {
        int b = idx / (KC * KC);
        int r = idx % (KC * KC);
        int i = r / KC, j = r % KC;
        float hd;
        if (i == j) {
            hd = DELTA_DIST * DELTA_DIST;
        } else {
            const float* ci = &s_c[(b * KC + i) * 17];
            const float* cj = &s_c[(b * KC + j) * 17];
            float sq = 0.f;
            for (int d = 0; d < D; ++d) { float df = ci[d] - cj[d]; sq += df * df; }
            float hh = fmaxf(DELTA_DIST - sqrtf(sq), 0.f);
            hd = hh * hh;
        }
        dacc += hd;
    }
    float total = acc + dacc / (2.f * KC * (KC - 1));

    for (int o = 32; o > 0; o >>= 1) total += __shfl_down(total, o, 64);
    if ((t & 63) == 0) s_red[t >> 6] = total;
    __syncthreads();
    if (t == 0) out[0] = (s_red[0] + s_red[1]) / (float)B;
}

extern "C" void kernel_launch(void* const* d_in, const int* in_sizes, int n_in,
                              void* d_out, int out_size, void* d_ws, size_t ws_size,
                              hipStream_t stream) {
    const float* data  = (const float*)d_in[0];
    const int* labels  = (const int*)d_in[1];
    float* ws = (float*)d_ws;
    float* g_sums = ws;                    // 1536
    float* g_cnt  = ws + B * KC * D;       // 96
    float* g_varp = g_cnt + B * KC;        // 64

    hipMemsetAsync(d_ws, 0, (B * KC * D + B * KC + 64) * sizeof(float), stream);

    k_sums<<<SBLOCKS, 256, 0, stream>>>(data, labels, g_sums, g_cnt);
    k_var <<<VBLOCKS, 256, 0, stream>>>(data, labels, g_sums, g_cnt, g_varp);
    k_final<<<1, 128, 0, stream>>>(g_sums, g_cnt, g_varp, (float*)d_out);
}

// Round 5
// 444.790 us; speedup vs baseline: 1.1345x; 1.1345x over previous
//
#include <hip/hip_runtime.h>
#include <math.h>

#define KC 24
constexpr int D = 16;
constexpr int B = 4;
constexpr int N = 512 * 1024;          // points per image, 2^19
constexpr float DELTA_VAR = 1.0f;
constexpr float DELTA_DIST = 2.0f;

constexpr int REP = 8;                 // LDS bin replicas (replica = lane&7)
constexpr int RS  = KC * 17;           // 408 words per sum replica
constexpr int CS  = 33;
constexpr int TPB = 1024;              // 16 waves/block
constexpr int GRID = 256;              // 1 block per CU (co-resident via coop launch)
constexpr int PPT = 8;                 // points per thread: 256*1024*8 = 2M = B*N

// ws (floats): g_sums [1536] | g_cnt [96] | g_varp [64] | g_bar [1 int]

__device__ inline unsigned pk_bf16(float a, float b) {  // RNE pack (a=low, b=high)
    unsigned ua = __float_as_uint(a), ub = __float_as_uint(b);
    ua += 0x7fffu + ((ua >> 16) & 1u);
    ub += 0x7fffu + ((ub >> 16) & 1u);
    return (ua >> 16) | (ub & 0xffff0000u);
}
__device__ inline float lo_bf16(unsigned u) { return __uint_as_float(u << 16); }
__device__ inline float hi_bf16(unsigned u) { return __uint_as_float(u & 0xffff0000u); }

// ------------- Fused: sums -> grid barrier -> hinged variance, ONE data read -------------
__global__ __launch_bounds__(TPB) void k_fused(const float* __restrict__ data,
                                               const int* __restrict__ labels,
                                               float* __restrict__ g_sums,
                                               float* __restrict__ g_cnt,
                                               float* __restrict__ g_varp,
                                               int* __restrict__ g_bar) {
    __shared__ float s_sum[REP * RS];     // 13 KB
    __shared__ float s_cnt[REP * CS];
    __shared__ float s_c[KC * 20];        // centers, b128-readable rows
    __shared__ float s_ic[KC];            // 1/count
    __shared__ float s_part[TPB / 64];
    const int t = threadIdx.x;
    for (int i = t; i < REP * RS; i += TPB) s_sum[i] = 0.f;
    for (int i = t; i < REP * CS; i += TPB) s_cnt[i] = 0.f;
    __syncthreads();

    const int p0 = (blockIdx.x * TPB + t) * PPT;   // 8 consecutive points, one image
    const int b  = p0 >> 19;
    const int n0 = p0 & (N - 1);

    const int4 la = *(const int4*)(labels + p0);
    const int4 lb = *(const int4*)(labels + p0 + 4);

    const int rb = (t & 7) * RS;
    const int ax0 = rb + la.x * 17, ax1 = rb + la.y * 17, ax2 = rb + la.z * 17, ax3 = rb + la.w * 17;
    const int ax4 = rb + lb.x * 17, ax5 = rb + lb.y * 17, ax6 = rb + lb.z * 17, ax7 = rb + lb.w * 17;

    unsigned u[D][4];                     // bf16x2 stash: 64 VGPRs
    const float* dp0 = data + (size_t)(b * D) * N + n0;
#pragma unroll
    for (int d = 0; d < D; ++d) {
        const float* dp = dp0 + (size_t)d * N;
        float4 v0 = *(const float4*)(dp);
        float4 v1 = *(const float4*)(dp + 4);
        atomicAdd(&s_sum[ax0 + d], v0.x);
        atomicAdd(&s_sum[ax1 + d], v0.y);
        atomicAdd(&s_sum[ax2 + d], v0.z);
        atomicAdd(&s_sum[ax3 + d], v0.w);
        atomicAdd(&s_sum[ax4 + d], v1.x);
        atomicAdd(&s_sum[ax5 + d], v1.y);
        atomicAdd(&s_sum[ax6 + d], v1.z);
        atomicAdd(&s_sum[ax7 + d], v1.w);
        u[d][0] = pk_bf16(v0.x, v0.y);
        u[d][1] = pk_bf16(v0.z, v0.w);
        u[d][2] = pk_bf16(v1.x, v1.y);
        u[d][3] = pk_bf16(v1.z, v1.w);
    }
    {
        const int cb = (t & 7) * CS;
        atomicAdd(&s_cnt[cb + la.x], 1.f);
        atomicAdd(&s_cnt[cb + la.y], 1.f);
        atomicAdd(&s_cnt[cb + la.z], 1.f);
        atomicAdd(&s_cnt[cb + la.w], 1.f);
        atomicAdd(&s_cnt[cb + lb.x], 1.f);
        atomicAdd(&s_cnt[cb + lb.y], 1.f);
        atomicAdd(&s_cnt[cb + lb.z], 1.f);
        atomicAdd(&s_cnt[cb + lb.w], 1.f);
    }
    __syncthreads();

    // block partials -> global (device-scope atomics)
    if (t < KC * D) {
        float s = 0.f;
#pragma unroll
        for (int r = 0; r < REP; ++r) s += s_sum[r * RS + (t >> 4) * 17 + (t & 15)];
        atomicAdd(&g_sums[b * (KC * D) + t], s);
    } else if (t < KC * D + KC) {
        const int k = t - KC * D;
        float s = 0.f;
#pragma unroll
        for (int r = 0; r < REP; ++r) s += s_cnt[r * CS + k];
        atomicAdd(&g_cnt[b * KC + k], s);
    }

    // ---- grid-wide barrier (all 256 blocks co-resident) ----
    __threadfence();
    __syncthreads();
    if (t == 0) {
        __hip_atomic_fetch_add(g_bar, 1, __ATOMIC_ACQ_REL, __HIP_MEMORY_SCOPE_AGENT);
        while (__hip_atomic_load(g_bar, __ATOMIC_ACQUIRE, __HIP_MEMORY_SCOPE_AGENT) < GRID)
            __builtin_amdgcn_s_sleep(2);
    }
    __syncthreads();

    // centers (agent-scope loads: bypass any stale cached lines)
    if (t < KC)
        s_ic[t] = 1.0f / __hip_atomic_load(&g_cnt[b * KC + t],
                                           __ATOMIC_RELAXED, __HIP_MEMORY_SCOPE_AGENT);
    __syncthreads();
    if (t < KC * D) {
        float s = __hip_atomic_load(&g_sums[b * (KC * D) + t],
                                    __ATOMIC_RELAXED, __HIP_MEMORY_SCOPE_AGENT);
        s_c[(t >> 4) * 20 + (t & 15)] = s * s_ic[t >> 4];
    }
    __syncthreads();

    // ---- phase 2: hinge from register-held bf16; var = sum h^2 / cnt[lab] ----
    float hsum = 0.f;
#define PT(LAB, HALF, J) do {                                             \
        const float* cp = &s_c[(LAB) * 20];                               \
        float ce[D];                                                      \
        _Pragma("unroll")                                                 \
        for (int d4 = 0; d4 < 4; ++d4) {                                  \
            float4 cv = *(const float4*)(cp + 4 * d4);                    \
            ce[4 * d4] = cv.x; ce[4 * d4 + 1] = cv.y;                     \
            ce[4 * d4 + 2] = cv.z; ce[4 * d4 + 3] = cv.w;                 \
        }                                                                 \
        float q = 0.f;                                                    \
        _Pragma("unroll")                                                 \
        for (int d = 0; d < D; ++d) {                                     \
            float x = (HALF) ? hi_bf16(u[d][J]) : lo_bf16(u[d][J]);       \
            float df = x - ce[d]; q += df * df;                           \
        }                                                                 \
        float h = fmaxf(sqrtf(q) - DELTA_VAR, 0.f);                       \
        hsum += h * h * s_ic[LAB];                                        \
    } while (0)

    PT(la.x, 0, 0); PT(la.y, 1, 0);
    PT(la.z, 0, 1); PT(la.w, 1, 1);
    PT(lb.x, 0, 2); PT(lb.y, 1, 2);
    PT(lb.z, 0, 3); PT(lb.w, 1, 3);
#undef PT

    for (int o = 32; o > 0; o >>= 1) hsum += __shfl_down(hsum, o, 64);
    if ((t & 63) == 0) s_part[t >> 6] = hsum;
    __syncthreads();
    if (t == 0) {
        float s = 0.f;
#pragma unroll
        for (int w = 0; w < TPB / 64; ++w) s += s_part[w];
        atomicAdd(&g_varp[blockIdx.x & 63], s);
    }
}

// ---------------- Finalize ----------------
__global__ __launch_bounds__(128) void k_final(const float* __restrict__ g_sums,
                                               const float* __restrict__ g_cnt,
                                               const float* __restrict__ g_varp,
                                               float* __restrict__ out) {
    __shared__ float s_c[B * KC * 17];
    __shared__ float s_red[2];
    const int t = threadIdx.x;

    float acc = 0.f;
    if (t < B * KC) {
        float cnt = g_cnt[t];
        float ns = 0.f;
        for (int d = 0; d < D; ++d) {
            float c = g_sums[t * D + d] / cnt;
            s_c[t * 17 + d] = c;
            ns += c * c;
        }
        acc = sqrtf(ns) / (float)KC;     // reg term
    }
    if (t < 64) acc += g_varp[t];        // var term partials
    __syncthreads();

    float dacc = 0.f;  // raw sum over [B,K,K] incl. diagonal (= delta_dist^2 each)
    for (int idx = t; idx < B * KC * KC; idx += 128) {
        int b = idx / (KC * KC);
        int r = idx % (KC * KC);
        int i = r / KC, j = r % KC;
        float hd;
        if (i == j) {
            hd = DELTA_DIST * DELTA_DIST;
        } else {
            const float* ci = &s_c[(b * KC + i) * 17];
            const float* cj = &s_c[(b * KC + j) * 17];
            float sq = 0.f;
            for (int d = 0; d < D; ++d) { float df = ci[d] - cj[d]; sq += df * df; }
            float hh = fmaxf(DELTA_DIST - sqrtf(sq), 0.f);
            hd = hh * hh;
        }
        dacc += hd;
    }
    float total = acc + dacc / (2.f * KC * (KC - 1));

    for (int o = 32; o > 0; o >>= 1) total += __shfl_down(total, o, 64);
    if ((t & 63) == 0) s_red[t >> 6] = total;
    __syncthreads();
    if (t == 0) out[0] = (s_red[0] + s_red[1]) / (float)B;
}

extern "C" void kernel_launch(void* const* d_in, const int* in_sizes, int n_in,
                              void* d_out, int out_size, void* d_ws, size_t ws_size,
                              hipStream_t stream) {
    const float* data  = (const float*)d_in[0];
    const int* labels  = (const int*)d_in[1];
    float* ws = (float*)d_ws;
    float* g_sums = ws;                    // 1536
    float* g_cnt  = ws + B * KC * D;       // 96
    float* g_varp = g_cnt + B * KC;        // 64
    int*   g_bar  = (int*)(g_varp + 64);   // 1

    hipMemsetAsync(d_ws, 0, (B * KC * D + B * KC + 64 + 4) * sizeof(float), stream);

    void* args[] = {(void*)&data, (void*)&labels, (void*)&g_sums,
                    (void*)&g_cnt, (void*)&g_varp, (void*)&g_bar};
    hipLaunchCooperativeKernel((const void*)k_fused, dim3(GRID), dim3(TPB),
                               args, 0, stream);
    k_final<<<1, 128, 0, stream>>>(g_sums, g_cnt, g_varp, (float*)d_out);
}

// Round 6
// 401.325 us; speedup vs baseline: 1.2574x; 1.1083x over previous
//
#include <hip/hip_runtime.h>
#include <math.h>

#define KC 24
constexpr int D = 16;
constexpr int B = 4;
constexpr int N = 512 * 1024;          // points per image, 2^19
constexpr float DELTA_VAR = 1.0f;
constexpr float DELTA_DIST = 2.0f;

constexpr int REP = 8;                 // LDS bin replicas (replica = lane&7)
constexpr int RS  = KC * 17;           // 408
constexpr int CS  = 33;
constexpr int TPB = 512;               // 8 waves; launch_bounds(512,2) -> 256 VGPR cap
constexpr int GRID = 256;              // capacity-guaranteed co-resident (see barrier note)
constexpr int GPT = 4;                 // point-groups per thread (4 pts each) = 16 pts/thread
constexpr int GSTRIDE = TPB * 4;       // 2048 points between a thread's groups
constexpr int BPTS = TPB * GPT * 4;    // 8192 points per block; 64 blocks per image

// ws (floats): g_sums [1536] | g_cnt [96] | g_varp [64] | g_bar [1 int]

__device__ inline unsigned pk_bf16(float a, float b) {  // RNE pack (a=low, b=high)
    unsigned ua = __float_as_uint(a), ub = __float_as_uint(b);
    ua += 0x7fffu + ((ua >> 16) & 1u);
    ub += 0x7fffu + ((ub >> 16) & 1u);
    return (ua >> 16) | (ub & 0xffff0000u);
}
__device__ inline float lo_bf16(unsigned u) { return __uint_as_float(u << 16); }
__device__ inline float hi_bf16(unsigned u) { return __uint_as_float(u & 0xffff0000u); }

// ------- Fused: sums -> grid barrier -> hinged variance; data read ONCE, stash in VGPRs -------
__global__ __launch_bounds__(TPB, 2) void k_fused(const float* __restrict__ data,
                                                  const int* __restrict__ labels,
                                                  float* __restrict__ g_sums,
                                                  float* __restrict__ g_cnt,
                                                  float* __restrict__ g_varp,
                                                  int* __restrict__ g_bar) {
    __shared__ float s_sum[REP * RS];     // 13 KB
    __shared__ float s_cnt[REP * CS];
    __shared__ float s_c[KC * 20];        // centers, b128-readable rows
    __shared__ float s_ic[KC];            // 1/count
    __shared__ float s_part[TPB / 64];
    const int t = threadIdx.x;
    for (int i = t; i < REP * RS; i += TPB) s_sum[i] = 0.f;
    for (int i = t; i < REP * CS; i += TPB) s_cnt[i] = 0.f;
    __syncthreads();

    const int base = blockIdx.x * BPTS;   // block's 8192 consecutive points, one image
    const int b    = base >> 19;
    const int n0   = (base & (N - 1)) + t * 4;

    int4 lab[GPT];
#pragma unroll
    for (int g = 0; g < GPT; ++g)
        lab[g] = *(const int4*)(labels + base + g * GSTRIDE + t * 4);

    const int rb = (t & 7) * RS;
    unsigned u[GPT][D][2];                // bf16x2 stash: 128 VGPRs

    const float* dp0 = data + (size_t)(b * D) * N + n0;
#pragma unroll
    for (int d = 0; d < D; ++d) {
        float4 v[GPT];
#pragma unroll
        for (int g = 0; g < GPT; ++g)     // 4 coalesced 16B loads in flight
            v[g] = *(const float4*)(dp0 + (size_t)d * N + g * GSTRIDE);
#pragma unroll
        for (int g = 0; g < GPT; ++g) {
            atomicAdd(&s_sum[rb + lab[g].x * 17 + d], v[g].x);
            atomicAdd(&s_sum[rb + lab[g].y * 17 + d], v[g].y);
            atomicAdd(&s_sum[rb + lab[g].z * 17 + d], v[g].z);
            atomicAdd(&s_sum[rb + lab[g].w * 17 + d], v[g].w);
            u[g][d][0] = pk_bf16(v[g].x, v[g].y);
            u[g][d][1] = pk_bf16(v[g].z, v[g].w);
        }
    }
    {
        const int cb = (t & 7) * CS;
#pragma unroll
        for (int g = 0; g < GPT; ++g) {
            atomicAdd(&s_cnt[cb + lab[g].x], 1.f);
            atomicAdd(&s_cnt[cb + lab[g].y], 1.f);
            atomicAdd(&s_cnt[cb + lab[g].z], 1.f);
            atomicAdd(&s_cnt[cb + lab[g].w], 1.f);
        }
    }
    __syncthreads();

    // block partials -> global (device-scope atomics)
    if (t < KC * D) {
        float s = 0.f;
#pragma unroll
        for (int r = 0; r < REP; ++r) s += s_sum[r * RS + (t >> 4) * 17 + (t & 15)];
        atomicAdd(&g_sums[b * (KC * D) + t], s);
    } else if (t < KC * D + KC) {
        const int k = t - KC * D;
        float s = 0.f;
#pragma unroll
        for (int r = 0; r < REP; ++r) s += s_cnt[r * CS + k];
        atomicAdd(&g_cnt[b * KC + k], s);
    }

    // ---- grid-wide barrier ----
    // Deadlock-safe by capacity: at >128 VGPR each CU hosts exactly one 8-wave block
    // (256 blocks <-> 256 CUs); at <=128 VGPR, 2 blocks/CU x 128 CUs still holds all
    // 256. All blocks co-resident in every packing.
    __threadfence();
    __syncthreads();
    if (t == 0) {
        __hip_atomic_fetch_add(g_bar, 1, __ATOMIC_ACQ_REL, __HIP_MEMORY_SCOPE_AGENT);
        while (__hip_atomic_load(g_bar, __ATOMIC_ACQUIRE, __HIP_MEMORY_SCOPE_AGENT) < GRID)
            __builtin_amdgcn_s_sleep(2);
    }
    __syncthreads();

    // centers (agent-scope loads: coherent across XCDs)
    if (t < KC)
        s_ic[t] = 1.0f / __hip_atomic_load(&g_cnt[b * KC + t],
                                           __ATOMIC_RELAXED, __HIP_MEMORY_SCOPE_AGENT);
    __syncthreads();
    if (t < KC * D) {
        float s = __hip_atomic_load(&g_sums[b * (KC * D) + t],
                                    __ATOMIC_RELAXED, __HIP_MEMORY_SCOPE_AGENT);
        s_c[(t >> 4) * 20 + (t & 15)] = s * s_ic[t >> 4];
    }
    __syncthreads();

    // ---- phase 2: hinge from register-held bf16; var = sum h^2 / cnt[lab] ----
    float hsum = 0.f;
#define PT(LAB, G, R, HALF) do {                                          \
        const float* cp = &s_c[(LAB) * 20];                               \
        float ce[D];                                                      \
        _Pragma("unroll")                                                 \
        for (int d4 = 0; d4 < 4; ++d4) {                                  \
            float4 cv = *(const float4*)(cp + 4 * d4);                    \
            ce[4 * d4] = cv.x; ce[4 * d4 + 1] = cv.y;                     \
            ce[4 * d4 + 2] = cv.z; ce[4 * d4 + 3] = cv.w;                 \
        }                                                                 \
        float q = 0.f;                                                    \
        _Pragma("unroll")                                                 \
        for (int d = 0; d < D; ++d) {                                     \
            float x = (HALF) ? hi_bf16(u[G][d][R]) : lo_bf16(u[G][d][R]); \
            float df = x - ce[d]; q += df * df;                           \
        }                                                                 \
        float h = fmaxf(sqrtf(q) - DELTA_VAR, 0.f);                       \
        hsum += h * h * s_ic[LAB];                                        \
    } while (0)

#pragma unroll
    for (int g = 0; g < GPT; ++g) {
        PT(lab[g].x, g, 0, 0);
        PT(lab[g].y, g, 0, 1);
        PT(lab[g].z, g, 1, 0);
        PT(lab[g].w, g, 1, 1);
    }
#undef PT

    for (int o = 32; o > 0; o >>= 1) hsum += __shfl_down(hsum, o, 64);
    if ((t & 63) == 0) s_part[t >> 6] = hsum;
    __syncthreads();
    if (t == 0) {
        float s = 0.f;
#pragma unroll
        for (int w = 0; w < TPB / 64; ++w) s += s_part[w];
        atomicAdd(&g_varp[blockIdx.x & 63], s);
    }
}

// ---------------- Finalize ----------------
__global__ __launch_bounds__(128) void k_final(const float* __restrict__ g_sums,
                                               const float* __restrict__ g_cnt,
                                               const float* __restrict__ g_varp,
                                               float* __restrict__ out) {
    __shared__ float s_c[B * KC * 17];
    __shared__ float s_red[2];
    const int t = threadIdx.x;

    float acc = 0.f;
    if (t < B * KC) {
        float cnt = g_cnt[t];
        float ns = 0.f;
        for (int d = 0; d < D; ++d) {
            float c = g_sums[t * D + d] / cnt;
            s_c[t * 17 + d] = c;
            ns += c * c;
        }
        acc = sqrtf(ns) / (float)KC;     // reg term
    }
    if (t < 64) acc += g_varp[t];        // var term partials
    __syncthreads();

    float dacc = 0.f;  // raw sum over [B,K,K] incl. diagonal (= delta_dist^2 each)
    for (int idx = t; idx < B * KC * KC; idx += 128) {
        int b = idx / (KC * KC);
        int r = idx % (KC * KC);
        int i = r / KC, j = r % KC;
        float hd;
        if (i == j) {
            hd = DELTA_DIST * DELTA_DIST;
        } else {
            const float* ci = &s_c[(b * KC + i) * 17];
            const float* cj = &s_c[(b * KC + j) * 17];
            float sq = 0.f;
            for (int d = 0; d < D; ++d) { float df = ci[d] - cj[d]; sq += df * df; }
            float hh = fmaxf(DELTA_DIST - sqrtf(sq), 0.f);
            hd = hh * hh;
        }
        dacc += hd;
    }
    float total = acc + dacc / (2.f * KC * (KC - 1));

    for (int o = 32; o > 0; o >>= 1) total += __shfl_down(total, o, 64);
    if ((t & 63) == 0) s_red[t >> 6] = total;
    __syncthreads();
    if (t == 0) out[0] = (s_red[0] + s_red[1]) / (float)B;
}

extern "C" void kernel_launch(void* const* d_in, const int* in_sizes, int n_in,
                              void* d_out, int out_size, void* d_ws, size_t ws_size,
                              hipStream_t stream) {
    const float* data  = (const float*)d_in[0];
    const int* labels  = (const int*)d_in[1];
    float* ws = (float*)d_ws;
    float* g_sums = ws;                    // 1536
    float* g_cnt  = ws + B * KC * D;       // 96
    float* g_varp = g_cnt + B * KC;        // 64
    int*   g_bar  = (int*)(g_varp + 64);   // 1

    hipMemsetAsync(d_ws, 0, (B * KC * D + B * KC + 64 + 4) * sizeof(float), stream);

    k_fused<<<GRID, TPB, 0, stream>>>(data, labels, g_sums, g_cnt, g_varp, g_bar);
    k_final<<<1, 128, 0, stream>>>(g_sums, g_cnt, g_varp, (float*)d_out);
}